// Round 1
// baseline (285.947 us; speedup 1.0000x reference)
//
#include <hip/hip_runtime.h>

#define NB 1024
#define NPG 64
#define NUM_NODES (NB * NPG)
#define HID 256
#define H1DIM 128
#define NE 2097152

// ---------------------------------------------------------------------------
// Kernel 1: zero the degree array (ws is poisoned 0xAA before every call)
// ---------------------------------------------------------------------------
__global__ void zero_deg_kernel(unsigned int* __restrict__ deg) {
    int i = blockIdx.x * blockDim.x + threadIdx.x;
    deg[i] = 0u;
}

// ---------------------------------------------------------------------------
// Kernel 2: degree count over edge sources (first row of edge_index)
// ---------------------------------------------------------------------------
__global__ void degree_kernel(const int4* __restrict__ src4,
                              unsigned int* __restrict__ deg) {
    int e = blockIdx.x * blockDim.x + threadIdx.x;  // e < NE/4
    int4 v = src4[e];
    atomicAdd(&deg[v.x], 1u);
    atomicAdd(&deg[v.y], 1u);
    atomicAdd(&deg[v.z], 1u);
    atomicAdd(&deg[v.w], 1u);
}

// ---------------------------------------------------------------------------
// Kernel 3: connectivity feature. One block = one graph (64 nodes).
// Stable rank by (deg, original index); conn[g*64 + rank] = local_idx / 64.
// Matches jnp.lexsort((deg, batch)) semantics exactly.
// ---------------------------------------------------------------------------
__global__ void conn_kernel(const unsigned int* __restrict__ deg,
                            float* __restrict__ conn) {
    __shared__ unsigned int d[NPG];
    const int g = blockIdx.x;
    const int i = threadIdx.x;  // 0..63
    unsigned int di = deg[g * NPG + i];
    d[i] = di;
    __syncthreads();
    int rank = 0;
#pragma unroll 8
    for (int j = 0; j < NPG; ++j) {
        unsigned int dj = d[j];
        rank += (int)((dj < di) || (dj == di && j < i));
    }
    conn[g * NPG + rank] = (float)i * (1.0f / 64.0f);
}

// ---------------------------------------------------------------------------
// Kernel 4: fused MLP (257->128->128->1, SiLU) + per-graph softmax.
// One block (256 threads) per graph. Register tile: 4 nodes x 8 outputs.
// LDS: h1 64x132 (33.8KB) + W tile 32x128 (16.4KB) + x tile 64x36 (9.2KB)
//      + conn/logits (0.5KB) = 59.9KB -> 2 blocks/CU.
// ---------------------------------------------------------------------------
__global__ __launch_bounds__(256, 2) void mlp_softmax_kernel(
    const float* __restrict__ feat,
    const float* __restrict__ W1,
    const float* __restrict__ b1,
    const float* __restrict__ W2,
    const float* __restrict__ b2,
    const float* __restrict__ W3,
    const float* __restrict__ b3,
    const float* __restrict__ kT,
    const float* __restrict__ conn,
    float* __restrict__ out)
{
    __shared__ float h1s[NPG][H1DIM + 4];  // stride 132: (n*132+k)%32 varies -> 2-way max (free)
    __shared__ float ws[32][H1DIM];        // weight k-tile
    __shared__ float xs[NPG][36];          // feature k-tile, padded
    __shared__ float conns[NPG];
    __shared__ float logits_s[NPG];

    const int g = blockIdx.x;
    const int tid = threadIdx.x;
    const int o_grp = tid & 15;    // 16 output groups of 8
    const int n_grp = tid >> 4;    // 16 node groups of 4
    const int n_base = n_grp * 4;
    const int o_base = o_grp * 8;
    const int node0 = g * NPG;

    if (tid < NPG) conns[tid] = conn[node0 + tid];
    __syncthreads();

    // ---- Layer 1 accumulator init: b1 + conn * W1[row 0] (the conn column)
    float acc[4][8];
    {
        float cv[4];
#pragma unroll
        for (int i = 0; i < 4; ++i) cv[i] = conns[n_base + i];
#pragma unroll
        for (int j = 0; j < 8; ++j) {
            float w0 = W1[o_base + j];   // row k=0
            float bb = b1[o_base + j];
#pragma unroll
            for (int i = 0; i < 4; ++i) acc[i][j] = fmaf(cv[i], w0, bb);
        }
    }

    const float* W1f = W1 + H1DIM;  // rows 1..256 (feature part), row-major [256][128]

    // ---- Layer 1 main loop: 8 k-tiles of 32 features
    for (int ft = 0; ft < 8; ++ft) {
        __syncthreads();  // previous tile's xs/ws reads complete
        // stage x tile: 64 rows x 32 floats (2 float4 per thread, coalesced)
#pragma unroll
        for (int r = 0; r < 2; ++r) {
            int ii = tid + r * 256;
            int row = ii >> 3;
            int c4 = (ii & 7) * 4;
            *(float4*)&xs[row][c4] =
                *(const float4*)&feat[(node0 + row) * HID + ft * 32 + c4];
        }
        // stage W1 tile: 32 rows x 128 cols (4 float4 per thread, coalesced)
#pragma unroll
        for (int r = 0; r < 4; ++r) {
            int ii = tid + r * 256;
            int kk = ii >> 5;
            int o4 = (ii & 31) * 4;
            *(float4*)&ws[kk][o4] =
                *(const float4*)&W1f[(ft * 32 + kk) * H1DIM + o4];
        }
        __syncthreads();
#pragma unroll 2
        for (int kk = 0; kk < 32; ++kk) {
            float4 wA = *(const float4*)&ws[kk][o_base];
            float4 wB = *(const float4*)&ws[kk][o_base + 4];
            float xv[4];
#pragma unroll
            for (int i = 0; i < 4; ++i) xv[i] = xs[n_base + i][kk];
#pragma unroll
            for (int i = 0; i < 4; ++i) {
                acc[i][0] = fmaf(xv[i], wA.x, acc[i][0]);
                acc[i][1] = fmaf(xv[i], wA.y, acc[i][1]);
                acc[i][2] = fmaf(xv[i], wA.z, acc[i][2]);
                acc[i][3] = fmaf(xv[i], wA.w, acc[i][3]);
                acc[i][4] = fmaf(xv[i], wB.x, acc[i][4]);
                acc[i][5] = fmaf(xv[i], wB.y, acc[i][5]);
                acc[i][6] = fmaf(xv[i], wB.z, acc[i][6]);
                acc[i][7] = fmaf(xv[i], wB.w, acc[i][7]);
            }
        }
    }

    // ---- SiLU -> h1 in LDS
#pragma unroll
    for (int i = 0; i < 4; ++i) {
        float t[8];
#pragma unroll
        for (int j = 0; j < 8; ++j) {
            float v = acc[i][j];
            t[j] = v / (1.0f + __expf(-v));
        }
        *(float4*)&h1s[n_base + i][o_base]     = make_float4(t[0], t[1], t[2], t[3]);
        *(float4*)&h1s[n_base + i][o_base + 4] = make_float4(t[4], t[5], t[6], t[7]);
    }

    // ---- Layer 2: 4 k-tiles of 32
    float acc2[4][8];
#pragma unroll
    for (int j = 0; j < 8; ++j) {
        float bb = b2[o_base + j];
#pragma unroll
        for (int i = 0; i < 4; ++i) acc2[i][j] = bb;
    }

    for (int kt = 0; kt < 4; ++kt) {
        __syncthreads();  // h1s writes visible; previous ws reads complete
#pragma unroll
        for (int r = 0; r < 4; ++r) {
            int ii = tid + r * 256;
            int kk = ii >> 5;
            int o4 = (ii & 31) * 4;
            *(float4*)&ws[kk][o4] =
                *(const float4*)&W2[(kt * 32 + kk) * H1DIM + o4];
        }
        __syncthreads();
#pragma unroll 2
        for (int kk = 0; kk < 32; ++kk) {
            float4 wA = *(const float4*)&ws[kk][o_base];
            float4 wB = *(const float4*)&ws[kk][o_base + 4];
            float xv[4];
#pragma unroll
            for (int i = 0; i < 4; ++i) xv[i] = h1s[n_base + i][kt * 32 + kk];
#pragma unroll
            for (int i = 0; i < 4; ++i) {
                acc2[i][0] = fmaf(xv[i], wA.x, acc2[i][0]);
                acc2[i][1] = fmaf(xv[i], wA.y, acc2[i][1]);
                acc2[i][2] = fmaf(xv[i], wA.z, acc2[i][2]);
                acc2[i][3] = fmaf(xv[i], wA.w, acc2[i][3]);
                acc2[i][4] = fmaf(xv[i], wB.x, acc2[i][4]);
                acc2[i][5] = fmaf(xv[i], wB.y, acc2[i][5]);
                acc2[i][6] = fmaf(xv[i], wB.z, acc2[i][6]);
                acc2[i][7] = fmaf(xv[i], wB.w, acc2[i][7]);
            }
        }
    }

    // ---- Layer 3: SiLU(h2) . W3, reduced across the 16 o-groups via shuffles
    float w3r[8];
#pragma unroll
    for (int j = 0; j < 8; ++j) w3r[j] = W3[o_base + j];
    float lg[4];
#pragma unroll
    for (int i = 0; i < 4; ++i) {
        float s = 0.0f;
#pragma unroll
        for (int j = 0; j < 8; ++j) {
            float v = acc2[i][j];
            float h = v / (1.0f + __expf(-v));
            s = fmaf(h, w3r[j], s);
        }
        lg[i] = s;
    }
    // o_grp lives in the low 4 lane bits -> xor-reduce within 16-lane groups
#pragma unroll
    for (int m = 1; m < 16; m <<= 1) {
#pragma unroll
        for (int i = 0; i < 4; ++i) lg[i] += __shfl_xor(lg[i], m, 64);
    }
    if (o_grp == 0) {
        float inv_kT = 1.0f / kT[0];
        float b3v = b3[0];
#pragma unroll
        for (int i = 0; i < 4; ++i)
            logits_s[n_base + i] = (lg[i] + b3v) * inv_kT;
    }
    __syncthreads();

    // ---- per-graph softmax over 64 nodes (wave 0 only)
    if (tid < NPG) {
        float v = logits_s[tid];
        float m = v;
#pragma unroll
        for (int s = 1; s < 64; s <<= 1) m = fmaxf(m, __shfl_xor(m, s, 64));
        float e = __expf(v - m);
        float sum = e;
#pragma unroll
        for (int s = 1; s < 64; s <<= 1) sum += __shfl_xor(sum, s, 64);
        out[node0 + tid] = e / sum;
    }
}

// ---------------------------------------------------------------------------
extern "C" void kernel_launch(void* const* d_in, const int* in_sizes, int n_in,
                              void* d_out, int out_size, void* d_ws, size_t ws_size,
                              hipStream_t stream)
{
    const float* feat = (const float*)d_in[0];
    const float* W1   = (const float*)d_in[1];
    const float* b1   = (const float*)d_in[2];
    const float* W2   = (const float*)d_in[3];
    const float* b2   = (const float*)d_in[4];
    const float* W3   = (const float*)d_in[5];
    const float* b3   = (const float*)d_in[6];
    const float* kT   = (const float*)d_in[7];
    const int*   ei   = (const int*)d_in[8];   // edge_index [2][E]; row 0 = sources
    // d_in[9] = batch: structure is repeat(arange(1024), 64) -> implicit

    float* out = (float*)d_out;

    unsigned int* deg = (unsigned int*)d_ws;                       // 65536 u32
    float* conn = (float*)((char*)d_ws + NUM_NODES * sizeof(unsigned int));  // 65536 f32

    zero_deg_kernel<<<NUM_NODES / 256, 256, 0, stream>>>(deg);
    degree_kernel<<<(NE / 4) / 256, 256, 0, stream>>>((const int4*)ei, deg);
    conn_kernel<<<NB, NPG, 0, stream>>>(deg, conn);
    mlp_softmax_kernel<<<NB, 256, 0, stream>>>(feat, W1, b1, W2, b2, W3, b3,
                                               kT, conn, out);
}

// Round 2
// 206.184 us; speedup vs baseline: 1.3869x; 1.3869x over previous
//
#include <hip/hip_runtime.h>

#define NB 1024
#define NPG 64
#define NUM_NODES (NB * NPG)
#define HID 256
#define H1DIM 128
#define NE 2097152
#define KT 16  // layer-1 k-tile

// ---------------------------------------------------------------------------
// Kernel 1: partial degree histograms, no global atomics.
// Grid = 2*C blocks of 1024 threads. Block bx: chunk c = bx>>1, half r = bx&1.
// LDS: 64KB packed u16 histogram over 32K nodes (half the node space).
// partials[c*32768 + r*16384 + w] = packed counts for node pair (2w, 2w+1)
// of half r from edge chunk c.  Every word is written -> no pre-zeroing of ws.
// ---------------------------------------------------------------------------
__global__ __launch_bounds__(1024) void hist_kernel(
    const int4* __restrict__ src4, unsigned int* __restrict__ partials, int C)
{
    __shared__ unsigned int h[16384];  // 64 KB: 32768 u16 counters
    const int bx = blockIdx.x;
    const int c = bx >> 1;
    const int r = bx & 1;
    const int tid = threadIdx.x;

    for (int i = tid; i < 16384; i += 1024) h[i] = 0u;
    __syncthreads();

    const int n4 = (NE / 4) / C;           // int4s per chunk
    const int4* p = src4 + c * n4;
    const int rbase = r << 15;             // node range [rbase, rbase+32768)
    for (int i = tid; i < n4; i += 1024) {
        int4 v = p[i];
        int s;
        s = v.x; if ((s >> 15) == r) atomicAdd(&h[(s & 32767) >> 1], 1u << ((s & 1) * 16));
        s = v.y; if ((s >> 15) == r) atomicAdd(&h[(s & 32767) >> 1], 1u << ((s & 1) * 16));
        s = v.z; if ((s >> 15) == r) atomicAdd(&h[(s & 32767) >> 1], 1u << ((s & 1) * 16));
        s = v.w; if ((s >> 15) == r) atomicAdd(&h[(s & 32767) >> 1], 1u << ((s & 1) * 16));
    }
    (void)rbase;
    __syncthreads();

    unsigned int* dst = partials + c * 32768 + r * 16384;
    for (int i = tid; i < 16384; i += 1024) dst[i] = h[i];
}

// ---------------------------------------------------------------------------
// Kernel 2: fused degree-reduce + conn + MLP (257->128->128->1 silu) + softmax.
// One block (256 thr = 4 waves) per graph. lane = node (64), wave owns a
// 32-wide output slice -> W rows are wave-uniform -> scalar (s_load) path,
// zero LDS traffic for weights.
// LDS: xs 64x20 (5.1KB, stride 20 for aligned b128 + even bank spread),
//      h1 64x132 (33.8KB), degs/conns 0.5KB; lpart aliases xs. ~39.4KB
//      -> 4 blocks/CU (16 waves/CU).
// ---------------------------------------------------------------------------
__global__ __launch_bounds__(256, 4) void mlp_softmax_kernel(
    const float* __restrict__ feat,
    const float* __restrict__ W1, const float* __restrict__ b1,
    const float* __restrict__ W2, const float* __restrict__ b2,
    const float* __restrict__ W3, const float* __restrict__ b3,
    const float* __restrict__ kT,
    const unsigned int* __restrict__ partials, int C,
    float* __restrict__ out)
{
    __shared__ float xs[NPG][20];          // layer-1 k-tile, padded stride 20
    __shared__ float h1s[NPG][132];        // h1, padded stride 132
    __shared__ unsigned int degs[NPG];
    __shared__ float conns[NPG];

    float (*lpart)[NPG] = reinterpret_cast<float(*)[NPG]>(&xs[0][0]);  // aliases xs (dead by then)

    const int tid = threadIdx.x;
    const int lane = tid & 63;
    const int w = __builtin_amdgcn_readfirstlane(tid >> 6);  // wave id, provably uniform
    const int g = blockIdx.x;
    const int node0 = g * NPG;

    // ---- degree reduce (sum C packed partials) + stable rank -> conn
    if (tid < 32) {
        unsigned int s = 0;
        for (int c = 0; c < C; ++c) s += partials[c * 32768 + g * 32 + tid];
        degs[2 * tid]     = s & 0xffffu;
        degs[2 * tid + 1] = s >> 16;
    }
    __syncthreads();
    if (tid < NPG) {
        unsigned int di = degs[tid];
        int rk = 0;
#pragma unroll 8
        for (int j = 0; j < NPG; ++j) {
            unsigned int dj = degs[j];
            rk += (int)((dj < di) || (dj == di && j < tid));
        }
        conns[rk] = (float)tid * (1.0f / 64.0f);
    }
    __syncthreads();
    const float cv = conns[lane];

    // ---- layer 1: acc over this wave's 32 outputs (4 groups of 8)
    float acc[4][8];
    {
        const float* b1w  = b1 + w * 32;
        const float* w1r0 = W1 + w * 32;   // row k=0 = conn column weights
#pragma unroll
        for (int i = 0; i < 4; ++i)
#pragma unroll
            for (int j = 0; j < 8; ++j)
                acc[i][j] = fmaf(cv, w1r0[i * 8 + j], b1w[i * 8 + j]);
    }

    const float* W1f = W1 + H1DIM;  // feature rows 1..256, row-major [256][128]

    for (int kt = 0; kt < HID / KT; ++kt) {
        __syncthreads();  // previous tile's reads done
        {
            int row = tid >> 2, c4 = (tid & 3) << 2;
            *(float4*)&xs[row][c4] =
                *(const float4*)&feat[(node0 + row) * HID + kt * KT + c4];
        }
        __syncthreads();
        const float* Wt = W1f + (kt * KT) * H1DIM + w * 32;
#pragma unroll
        for (int k4 = 0; k4 < KT / 4; ++k4) {
            float4 xv = *(const float4*)&xs[lane][k4 * 4];
#pragma unroll
            for (int kk = 0; kk < 4; ++kk) {
                float xk = (kk == 0) ? xv.x : (kk == 1) ? xv.y : (kk == 2) ? xv.z : xv.w;
                const float* wr = Wt + (k4 * 4 + kk) * H1DIM;
#pragma unroll
                for (int i = 0; i < 4; ++i)
#pragma unroll
                    for (int j = 0; j < 8; ++j)
                        acc[i][j] = fmaf(xk, wr[i * 8 + j], acc[i][j]);
            }
        }
    }

    // ---- SiLU -> h1s[lane][w*32 ...]
#pragma unroll
    for (int i = 0; i < 4; ++i) {
        float t0[8];
#pragma unroll
        for (int j = 0; j < 8; ++j) {
            float v = acc[i][j];
            t0[j] = v / (1.0f + __expf(-v));
        }
        *(float4*)&h1s[lane][w * 32 + i * 8]     = make_float4(t0[0], t0[1], t0[2], t0[3]);
        *(float4*)&h1s[lane][w * 32 + i * 8 + 4] = make_float4(t0[4], t0[5], t0[6], t0[7]);
    }
    __syncthreads();

    // ---- layer 2: full K=128 from LDS, W2 rows scalar
    float acc2[4][8];
    {
        const float* b2w = b2 + w * 32;
#pragma unroll
        for (int i = 0; i < 4; ++i)
#pragma unroll
            for (int j = 0; j < 8; ++j) acc2[i][j] = b2w[i * 8 + j];
    }
    const float* W2w = W2 + w * 32;
#pragma unroll 2
    for (int k4 = 0; k4 < H1DIM / 4; ++k4) {
        float4 xv = *(const float4*)&h1s[lane][k4 * 4];
#pragma unroll
        for (int kk = 0; kk < 4; ++kk) {
            float xk = (kk == 0) ? xv.x : (kk == 1) ? xv.y : (kk == 2) ? xv.z : xv.w;
            const float* wr = W2w + (k4 * 4 + kk) * H1DIM;
#pragma unroll
            for (int i = 0; i < 4; ++i)
#pragma unroll
                for (int j = 0; j < 8; ++j)
                    acc2[i][j] = fmaf(xk, wr[i * 8 + j], acc2[i][j]);
        }
    }

    // ---- layer 3 partial: silu(h2) . W3 over this wave's 32 dims
    {
        const float* W3w = W3 + w * 32;
        float lg = 0.0f;
#pragma unroll
        for (int i = 0; i < 4; ++i)
#pragma unroll
            for (int j = 0; j < 8; ++j) {
                float v = acc2[i][j];
                float hh = v / (1.0f + __expf(-v));
                lg = fmaf(hh, W3w[i * 8 + j], lg);
            }
        lpart[w][lane] = lg;
    }
    __syncthreads();

    // ---- cross-wave reduce + per-graph softmax (wave 0)
    if (tid < NPG) {
        float s = lpart[0][tid] + lpart[1][tid] + lpart[2][tid] + lpart[3][tid];
        s = (s + b3[0]) / kT[0];
        float m = s;
#pragma unroll
        for (int d = 1; d < 64; d <<= 1) m = fmaxf(m, __shfl_xor(m, d, 64));
        float e = __expf(s - m);
        float su = e;
#pragma unroll
        for (int d = 1; d < 64; d <<= 1) su += __shfl_xor(su, d, 64);
        out[node0 + tid] = e / su;
    }
}

// ---------------------------------------------------------------------------
extern "C" void kernel_launch(void* const* d_in, const int* in_sizes, int n_in,
                              void* d_out, int out_size, void* d_ws, size_t ws_size,
                              hipStream_t stream)
{
    const float* feat = (const float*)d_in[0];
    const float* W1   = (const float*)d_in[1];
    const float* b1   = (const float*)d_in[2];
    const float* W2   = (const float*)d_in[3];
    const float* b2   = (const float*)d_in[4];
    const float* W3   = (const float*)d_in[5];
    const float* b3   = (const float*)d_in[6];
    const float* kT   = (const float*)d_in[7];
    const int*   ei   = (const int*)d_in[8];   // edge_index [2][E]; row 0 = sources
    // d_in[9] = batch: repeat(arange(1024), 64) -> implicit

    float* out = (float*)d_out;
    unsigned int* partials = (unsigned int*)d_ws;

    // chunk count sized to available workspace (C*128KB partials)
    int C = 64;
    if (ws_size < (size_t)64 * 131072) C = 32;
    if (ws_size < (size_t)32 * 131072) C = 16;
    if (ws_size < (size_t)16 * 131072) C = 8;

    hist_kernel<<<2 * C, 1024, 0, stream>>>((const int4*)ei, partials, C);
    mlp_softmax_kernel<<<NB, 256, 0, stream>>>(feat, W1, b1, W2, b2, W3, b3,
                                               kT, partials, C, out);
}